// Round 1
// baseline (821.106 us; speedup 1.0000x reference)
//
#include <hip/hip_runtime.h>
#include <stdint.h>

#define T_DIM 8192
#define K_DIM 4096
#define N_DIM 4096
#define FP8MAX 448.0f

typedef __attribute__((ext_vector_type(4))) float floatx4;

// ---------- helpers ----------

__device__ static inline void load16_g2lds(const void* gptr, void* lptr) {
    __builtin_amdgcn_global_load_lds(
        (const __attribute__((address_space(1))) void*)gptr,
        (__attribute__((address_space(3))) void*)lptr,
        16, 0, 0);
}

// pack 4 floats -> 4 fp8 e4m3fn bytes (HW RNE cvt; OCP format on gfx950)
__device__ static inline uint32_t pack4_fp8(float f0, float f1, float f2, float f3) {
    int p = 0;
    p = __builtin_amdgcn_cvt_pk_fp8_f32(f0, f1, p, false); // bytes 0,1
    p = __builtin_amdgcn_cvt_pk_fp8_f32(f2, f3, p, true);  // bytes 2,3
    return (uint32_t)p;
}

// ---------- kernel 1: per-row dynamic quantization of x ----------
// one block (256 thr) per row; 4096 floats/row; writes fp8 row + scale
__global__ __launch_bounds__(256) void xquant_kernel(
    const float* __restrict__ x, uint8_t* __restrict__ xq,
    float* __restrict__ xscale)
{
    const int t = blockIdx.x;
    const int tid = threadIdx.x;
    const int lane = tid & 63;
    const int wave = tid >> 6;
    const float4* xr4 = (const float4*)(x + (size_t)t * K_DIM);

    float4 v[4];
    float m = 0.0f;
#pragma unroll
    for (int e = 0; e < 4; ++e) {
        v[e] = xr4[tid + e * 256];
        m = fmaxf(m, fmaxf(fmaxf(fabsf(v[e].x), fabsf(v[e].y)),
                           fmaxf(fabsf(v[e].z), fabsf(v[e].w))));
    }
    // wave reduce max (64 lanes)
#pragma unroll
    for (int off = 32; off > 0; off >>= 1)
        m = fmaxf(m, __shfl_down(m, off, 64));
    __shared__ float red[4];
    if (lane == 0) red[wave] = m;
    __syncthreads();
    float mm = fmaxf(fmaxf(red[0], red[1]), fmaxf(red[2], red[3]));
    // match reference exactly: scale = max/448 (fp32 div, RNE), floor 1e-12
    float scale = fmaxf(mm / FP8MAX, 1e-12f);
    if (tid == 0) xscale[t] = scale;

    uint32_t* xqr = (uint32_t*)(xq + (size_t)t * K_DIM);
#pragma unroll
    for (int e = 0; e < 4; ++e) {
        float q0 = fminf(fmaxf(v[e].x / scale, -FP8MAX), FP8MAX);
        float q1 = fminf(fmaxf(v[e].y / scale, -FP8MAX), FP8MAX);
        float q2 = fminf(fmaxf(v[e].z / scale, -FP8MAX), FP8MAX);
        float q3 = fminf(fmaxf(v[e].w / scale, -FP8MAX), FP8MAX);
        xqr[tid + e * 256] = pack4_fp8(q0, q1, q2, q3);
    }
}

// ---------- kernel 2: quantize w (per-tensor, plain cast) + transpose ----------
// w is [K][N] row-major fp32; produce wqT [N][K] fp8 so GEMM B-frags read
// contiguous k. 64x64 tiles via LDS.
__global__ __launch_bounds__(256) void wquant_kernel(
    const float* __restrict__ w, uint8_t* __restrict__ wqT)
{
    const int n0 = blockIdx.x * 64;
    const int k0 = blockIdx.y * 64;
    __shared__ __align__(16) uint8_t tile[64][68]; // +4 pad (keeps 4B align)

#pragma unroll
    for (int e = 0; e < 4; ++e) {
        int idx = threadIdx.x + e * 256; // 0..1023
        int r = idx >> 4;                // k within tile
        int c4 = idx & 15;               // float4 col group (n)
        float4 v = *(const float4*)(w + (size_t)(k0 + r) * N_DIM + n0 + c4 * 4);
        *(uint32_t*)&tile[r][c4 * 4] = pack4_fp8(v.x, v.y, v.z, v.w);
    }
    __syncthreads();
#pragma unroll
    for (int e = 0; e < 4; ++e) {
        int idx = threadIdx.x + e * 256;
        int rr = idx >> 4;  // n within tile
        int cc = idx & 15;  // k u32 group
        uint32_t b0 = tile[cc * 4 + 0][rr];
        uint32_t b1 = tile[cc * 4 + 1][rr];
        uint32_t b2 = tile[cc * 4 + 2][rr];
        uint32_t b3 = tile[cc * 4 + 3][rr];
        *(uint32_t*)(wqT + (size_t)(n0 + rr) * K_DIM + k0 + cc * 4) =
            b0 | (b1 << 8) | (b2 << 16) | (b3 << 24);
    }
}

// ---------- kernel 3: fp8 GEMM, m97 structure ----------
// C[m][n] = sum_k xq[m][k]*wqT[n][k]; epilogue scales by xscale[m]*wscale.
// 128x128 block tile, BK=64 bytes, 4 waves in 2x2 (64x64 each, 4x4 of 16x16).
__global__ __launch_bounds__(256) void gemm_fp8_kernel(
    const uint8_t* __restrict__ xq, const uint8_t* __restrict__ wqT,
    const float* __restrict__ xscale, const float* __restrict__ wscale,
    float* __restrict__ out)
{
    __shared__ __align__(16) uint8_t As[128 * 64]; // As[m][k], stride 64
    __shared__ __align__(16) uint8_t Bs[128 * 64]; // Bs[n][k], stride 64

    const int tid = threadIdx.x;
    const int lane = tid & 63;
    const int wave = tid >> 6;
    const int m0 = blockIdx.y * 128;
    const int n0 = blockIdx.x * 128;
    const int wm = (wave >> 1) * 64;
    const int wn = (wave & 1) * 64;
    const int row = lane & 15;
    const int quad = lane >> 4;

    floatx4 acc[4][4] = {{{0.f,0.f,0.f,0.f}}};

    // staging: 512 chunks of 16B per matrix; 2 per thread.
    const int c0 = tid, c1 = tid + 256;
    const uint8_t* gA0 = xq  + (size_t)(m0 + (c0 >> 2)) * K_DIM + (c0 & 3) * 16;
    const uint8_t* gA1 = xq  + (size_t)(m0 + (c1 >> 2)) * K_DIM + (c1 & 3) * 16;
    const uint8_t* gB0 = wqT + (size_t)(n0 + (c0 >> 2)) * K_DIM + (c0 & 3) * 16;
    const uint8_t* gB1 = wqT + (size_t)(n0 + (c1 >> 2)) * K_DIM + (c1 & 3) * 16;
    uint8_t* lA0 = As + c0 * 16;
    uint8_t* lA1 = As + c1 * 16;
    uint8_t* lB0 = Bs + c0 * 16;
    uint8_t* lB1 = Bs + c1 * 16;

    // LDS read offsets (bytes): frag = 8 contiguous k-bytes
    int aoff[4], boff[4];
#pragma unroll
    for (int i = 0; i < 4; ++i) {
        aoff[i] = (wm + i * 16 + row) * 64 + quad * 8;
        boff[i] = (wn + i * 16 + row) * 64 + quad * 8;
    }

    for (int k0 = 0; k0 < K_DIM; k0 += 64) {
        __syncthreads(); // previous compute done before overwrite
        load16_g2lds(gA0 + k0, lA0);
        load16_g2lds(gA1 + k0, lA1);
        load16_g2lds(gB0 + k0, lB0);
        load16_g2lds(gB1 + k0, lB1);
        __syncthreads(); // staging complete (compiler drains vmcnt)

#pragma unroll
        for (int kk = 0; kk < 64; kk += 32) {
            long a[4], b[4];
#pragma unroll
            for (int i = 0; i < 4; ++i)
                a[i] = *(const long*)(As + aoff[i] + kk);
#pragma unroll
            for (int j = 0; j < 4; ++j)
                b[j] = *(const long*)(Bs + boff[j] + kk);
#pragma unroll
            for (int i = 0; i < 4; ++i)
#pragma unroll
                for (int j = 0; j < 4; ++j)
                    acc[i][j] = __builtin_amdgcn_mfma_f32_16x16x32_fp8_fp8(
                        a[i], b[j], acc[i][j], 0, 0, 0);
        }
    }

    // epilogue: C/D layout col=lane&15, row=quad*4+reg (verified, dtype-indep)
    const float wsv = wscale[0];
#pragma unroll
    for (int i = 0; i < 4; ++i) {
        const int rbase = m0 + wm + i * 16 + quad * 4;
        float s[4];
#pragma unroll
        for (int r = 0; r < 4; ++r) s[r] = xscale[rbase + r] * wsv;
#pragma unroll
        for (int j = 0; j < 4; ++j) {
            const int col = n0 + wn + j * 16 + row;
#pragma unroll
            for (int r = 0; r < 4; ++r)
                out[(size_t)(rbase + r) * N_DIM + col] = acc[i][j][r] * s[r];
        }
    }
}

// ---------- launch ----------

extern "C" void kernel_launch(void* const* d_in, const int* in_sizes, int n_in,
                              void* d_out, int out_size, void* d_ws, size_t ws_size,
                              hipStream_t stream) {
    const float* x      = (const float*)d_in[0]; // [8192,4096] fp32
    const float* w      = (const float*)d_in[1]; // [4096,4096] fp32
    const float* wscale = (const float*)d_in[2]; // [1] fp32
    float* out = (float*)d_out;                  // [8192,4096] fp32

    uint8_t* xq  = (uint8_t*)d_ws;                       // 33.5 MB
    uint8_t* wqT = xq + (size_t)T_DIM * K_DIM;           // 16.8 MB
    float* xscale = (float*)(wqT + (size_t)N_DIM * K_DIM); // 32 KB

    xquant_kernel<<<T_DIM, 256, 0, stream>>>(x, xq, xscale);
    wquant_kernel<<<dim3(N_DIM / 64, K_DIM / 64), 256, 0, stream>>>(w, wqT);
    gemm_fp8_kernel<<<dim3(N_DIM / 128, T_DIM / 128), 256, 0, stream>>>(
        xq, wqT, xscale, wscale, out);
}

// Round 2
// 473.462 us; speedup vs baseline: 1.7343x; 1.7343x over previous
//
#include <hip/hip_runtime.h>
#include <stdint.h>

#define T_DIM 8192
#define K_DIM 4096
#define N_DIM 4096
#define FP8MAX 448.0f

typedef __attribute__((ext_vector_type(4))) float floatx4;
typedef __attribute__((ext_vector_type(2))) long longx2;

// ---------- helpers ----------

__device__ static inline void load16_g2lds(const void* gptr, void* lptr) {
    __builtin_amdgcn_global_load_lds(
        (const __attribute__((address_space(1))) void*)gptr,
        (__attribute__((address_space(3))) void*)lptr,
        16, 0, 0);
}

// pack 4 floats -> 4 fp8 e4m3fn bytes (HW RNE cvt; OCP format on gfx950)
__device__ static inline uint32_t pack4_fp8(float f0, float f1, float f2, float f3) {
    int p = 0;
    p = __builtin_amdgcn_cvt_pk_fp8_f32(f0, f1, p, false); // bytes 0,1
    p = __builtin_amdgcn_cvt_pk_fp8_f32(f2, f3, p, true);  // bytes 2,3
    return (uint32_t)p;
}

// ---------- kernel 1: per-row dynamic quantization of x ----------
__global__ __launch_bounds__(256) void xquant_kernel(
    const float* __restrict__ x, uint8_t* __restrict__ xq,
    float* __restrict__ xscale)
{
    const int t = blockIdx.x;
    const int tid = threadIdx.x;
    const int lane = tid & 63;
    const int wave = tid >> 6;
    const float4* xr4 = (const float4*)(x + (size_t)t * K_DIM);

    float4 v[4];
    float m = 0.0f;
#pragma unroll
    for (int e = 0; e < 4; ++e) {
        v[e] = xr4[tid + e * 256];
        m = fmaxf(m, fmaxf(fmaxf(fabsf(v[e].x), fabsf(v[e].y)),
                           fmaxf(fabsf(v[e].z), fabsf(v[e].w))));
    }
#pragma unroll
    for (int off = 32; off > 0; off >>= 1)
        m = fmaxf(m, __shfl_down(m, off, 64));
    __shared__ float red[4];
    if (lane == 0) red[wave] = m;
    __syncthreads();
    float mm = fmaxf(fmaxf(red[0], red[1]), fmaxf(red[2], red[3]));
    float scale = fmaxf(mm / FP8MAX, 1e-12f); // exact: stored & used for dequant
    if (tid == 0) xscale[t] = scale;
    const float inv = 1.0f / scale;          // 1 div instead of 16 per thread

    uint32_t* xqr = (uint32_t*)(xq + (size_t)t * K_DIM);
#pragma unroll
    for (int e = 0; e < 4; ++e) {
        float q0 = fminf(fmaxf(v[e].x * inv, -FP8MAX), FP8MAX);
        float q1 = fminf(fmaxf(v[e].y * inv, -FP8MAX), FP8MAX);
        float q2 = fminf(fmaxf(v[e].z * inv, -FP8MAX), FP8MAX);
        float q3 = fminf(fmaxf(v[e].w * inv, -FP8MAX), FP8MAX);
        xqr[tid + e * 256] = pack4_fp8(q0, q1, q2, q3);
    }
}

// ---------- kernel 2: quantize w (per-tensor cast) + transpose ----------
// w [K][N] fp32 -> wqT [N][K] fp8. Tile stored byte-transposed in LDS so the
// writer does one aligned b32 read (was 16 ds_read_u8).
__global__ __launch_bounds__(256) void wquant_kernel(
    const float* __restrict__ w, uint8_t* __restrict__ wqT)
{
    const int n0 = blockIdx.x * 64;
    const int k0 = blockIdx.y * 64;
    __shared__ __align__(4) uint8_t tile[64][68]; // [n][k], +4 pad

#pragma unroll
    for (int e = 0; e < 4; ++e) {
        int idx = threadIdx.x + e * 256; // 0..1023
        int r = idx >> 4;                // k within tile
        int c4 = idx & 15;               // n float4 group
        float4 v = *(const float4*)(w + (size_t)(k0 + r) * N_DIM + n0 + c4 * 4);
        uint32_t p = pack4_fp8(v.x, v.y, v.z, v.w);
        tile[c4 * 4 + 0][r] = (uint8_t)(p);
        tile[c4 * 4 + 1][r] = (uint8_t)(p >> 8);
        tile[c4 * 4 + 2][r] = (uint8_t)(p >> 16);
        tile[c4 * 4 + 3][r] = (uint8_t)(p >> 24);
    }
    __syncthreads();
#pragma unroll
    for (int e = 0; e < 4; ++e) {
        int idx = threadIdx.x + e * 256;
        int rr = idx >> 4;  // n within tile
        int cc = idx & 15;  // k u32 group
        uint32_t u = *(const uint32_t*)&tile[rr][cc * 4];
        *(uint32_t*)(wqT + (size_t)(n0 + rr) * K_DIM + k0 + cc * 4) = u;
    }
}

// ---------- kernel 3: fp8 GEMM ----------
// 128x128 tile, BK=64B, 4 waves 2x2. LDS XOR-16B swizzle + b128 frag reads.
// k-permutation trick: one b128 per frag row covers global k [quad*16,+16);
// lo 8B -> MFMA step 0, hi 8B -> step 1. Same permutation on A and B, so
// products pair correctly; union over quads+steps covers k 0..63 exactly once.
__global__ __launch_bounds__(256) void gemm_fp8_kernel(
    const uint8_t* __restrict__ xq, const uint8_t* __restrict__ wqT,
    const float* __restrict__ xscale, const float* __restrict__ wscale,
    float* __restrict__ out)
{
    __shared__ __align__(16) uint8_t As[128 * 64]; // [m][k-swizzled]
    __shared__ __align__(16) uint8_t Bs[128 * 64]; // [n][k-swizzled]

    const int tid = threadIdx.x;
    const int lane = tid & 63;
    const int wave = tid >> 6;
    const int m0 = blockIdx.y * 128;
    const int n0 = blockIdx.x * 128;
    const int wm = (wave >> 1) * 64;
    const int wn = (wave & 1) * 64;
    const int row = lane & 15;
    const int quad = lane >> 4;

    floatx4 acc[4][4] = {{{0.f,0.f,0.f,0.f}}};

    // staging: LDS slot c = (row, gg=c&3) holds global group g = gg ^ (row&3).
    // LDS dest stays lane-contiguous (HW constraint); global addr is per-lane.
    const int c0 = tid, c1 = tid + 256;
    const int r0 = c0 >> 2, g0 = (c0 & 3) ^ (r0 & 3);
    const int r1 = c1 >> 2, g1 = (c1 & 3) ^ (r1 & 3);
    const uint8_t* gA0 = xq  + (size_t)(m0 + r0) * K_DIM + g0 * 16;
    const uint8_t* gA1 = xq  + (size_t)(m0 + r1) * K_DIM + g1 * 16;
    const uint8_t* gB0 = wqT + (size_t)(n0 + r0) * K_DIM + g0 * 16;
    const uint8_t* gB1 = wqT + (size_t)(n0 + r1) * K_DIM + g1 * 16;
    uint8_t* lA0 = As + c0 * 16;
    uint8_t* lA1 = As + c1 * 16;
    uint8_t* lB0 = Bs + c0 * 16;
    uint8_t* lB1 = Bs + c1 * 16;

    // frag read offsets: b128 at m*64 + ((quad ^ (m&3))<<4)
    int aoff[4], boff[4];
#pragma unroll
    for (int i = 0; i < 4; ++i) {
        const int mr = wm + i * 16 + row;
        const int nr = wn + i * 16 + row;
        aoff[i] = mr * 64 + ((quad ^ (mr & 3)) << 4);
        boff[i] = nr * 64 + ((quad ^ (nr & 3)) << 4);
    }

    for (int k0 = 0; k0 < K_DIM; k0 += 64) {
        __syncthreads();
        load16_g2lds(gA0 + k0, lA0);
        load16_g2lds(gA1 + k0, lA1);
        load16_g2lds(gB0 + k0, lB0);
        load16_g2lds(gB1 + k0, lB1);
        __syncthreads();

        longx2 a[4], b[4];
#pragma unroll
        for (int i = 0; i < 4; ++i) a[i] = *(const longx2*)(As + aoff[i]);
#pragma unroll
        for (int j = 0; j < 4; ++j) b[j] = *(const longx2*)(Bs + boff[j]);
#pragma unroll
        for (int i = 0; i < 4; ++i)
#pragma unroll
            for (int j = 0; j < 4; ++j) {
                acc[i][j] = __builtin_amdgcn_mfma_f32_16x16x32_fp8_fp8(
                    a[i].x, b[j].x, acc[i][j], 0, 0, 0);
                acc[i][j] = __builtin_amdgcn_mfma_f32_16x16x32_fp8_fp8(
                    a[i].y, b[j].y, acc[i][j], 0, 0, 0);
            }
    }

    // epilogue: C/D layout col=lane&15, row=quad*4+reg (verified, dtype-indep)
    const float wsv = wscale[0];
#pragma unroll
    for (int i = 0; i < 4; ++i) {
        const int rbase = m0 + wm + i * 16 + quad * 4;
        float s[4];
#pragma unroll
        for (int r = 0; r < 4; ++r) s[r] = xscale[rbase + r] * wsv;
#pragma unroll
        for (int j = 0; j < 4; ++j) {
            const int col = n0 + wn + j * 16 + row;
#pragma unroll
            for (int r = 0; r < 4; ++r)
                out[(size_t)(rbase + r) * N_DIM + col] = acc[i][j][r] * s[r];
        }
    }
}

// ---------- launch ----------

extern "C" void kernel_launch(void* const* d_in, const int* in_sizes, int n_in,
                              void* d_out, int out_size, void* d_ws, size_t ws_size,
                              hipStream_t stream) {
    const float* x      = (const float*)d_in[0]; // [8192,4096] fp32
    const float* w      = (const float*)d_in[1]; // [4096,4096] fp32
    const float* wscale = (const float*)d_in[2]; // [1] fp32
    float* out = (float*)d_out;                  // [8192,4096] fp32

    uint8_t* xq  = (uint8_t*)d_ws;
    uint8_t* wqT = xq + (size_t)T_DIM * K_DIM;
    float* xscale = (float*)(wqT + (size_t)N_DIM * K_DIM);

    xquant_kernel<<<T_DIM, 256, 0, stream>>>(x, xq, xscale);
    wquant_kernel<<<dim3(N_DIM / 64, K_DIM / 64), 256, 0, stream>>>(w, wqT);
    gemm_fp8_kernel<<<dim3(N_DIM / 128, T_DIM / 128), 256, 0, stream>>>(
        xq, wqT, xscale, wscale, out);
}

// Round 3
// 408.401 us; speedup vs baseline: 2.0105x; 1.1593x over previous
//
#include <hip/hip_runtime.h>
#include <stdint.h>

#define T_DIM 8192
#define K_DIM 4096
#define N_DIM 4096
#define FP8MAX 448.0f

typedef __attribute__((ext_vector_type(4))) float floatx4;
typedef __attribute__((ext_vector_type(4))) int   intx4;
typedef __attribute__((ext_vector_type(8))) int   intx8;

// ---------- helpers ----------

__device__ static inline void load16_g2lds(const void* gptr, void* lptr) {
    __builtin_amdgcn_global_load_lds(
        (const __attribute__((address_space(1))) void*)gptr,
        (__attribute__((address_space(3))) void*)lptr,
        16, 0, 0);
}

// pack 4 floats -> 4 fp8 e4m3fn bytes (HW RNE cvt; OCP format on gfx950)
__device__ static inline uint32_t pack4_fp8(float f0, float f1, float f2, float f3) {
    int p = 0;
    p = __builtin_amdgcn_cvt_pk_fp8_f32(f0, f1, p, false); // bytes 0,1
    p = __builtin_amdgcn_cvt_pk_fp8_f32(f2, f3, p, true);  // bytes 2,3
    return (uint32_t)p;
}

// ---------- kernel 1: per-row dynamic quantization of x ----------
__global__ __launch_bounds__(256) void xquant_kernel(
    const float* __restrict__ x, uint8_t* __restrict__ xq,
    float* __restrict__ xscale)
{
    const int t = blockIdx.x;
    const int tid = threadIdx.x;
    const int lane = tid & 63;
    const int wave = tid >> 6;
    const float4* xr4 = (const float4*)(x + (size_t)t * K_DIM);

    float4 v[4];
    float m = 0.0f;
#pragma unroll
    for (int e = 0; e < 4; ++e) {
        v[e] = xr4[tid + e * 256];
        m = fmaxf(m, fmaxf(fmaxf(fabsf(v[e].x), fabsf(v[e].y)),
                           fmaxf(fabsf(v[e].z), fabsf(v[e].w))));
    }
#pragma unroll
    for (int off = 32; off > 0; off >>= 1)
        m = fmaxf(m, __shfl_down(m, off, 64));
    __shared__ float red[4];
    if (lane == 0) red[wave] = m;
    __syncthreads();
    float mm = fmaxf(fmaxf(red[0], red[1]), fmaxf(red[2], red[3]));
    float scale = fmaxf(mm / FP8MAX, 1e-12f); // exact: stored & used for dequant
    if (tid == 0) xscale[t] = scale;
    const float inv = 1.0f / scale;

    uint32_t* xqr = (uint32_t*)(xq + (size_t)t * K_DIM);
#pragma unroll
    for (int e = 0; e < 4; ++e) {
        float q0 = fminf(fmaxf(v[e].x * inv, -FP8MAX), FP8MAX);
        float q1 = fminf(fmaxf(v[e].y * inv, -FP8MAX), FP8MAX);
        float q2 = fminf(fmaxf(v[e].z * inv, -FP8MAX), FP8MAX);
        float q3 = fminf(fmaxf(v[e].w * inv, -FP8MAX), FP8MAX);
        xqr[tid + e * 256] = pack4_fp8(q0, q1, q2, q3);
    }
}

// ---------- kernel 2: quantize w + transpose, u32-granular ----------
// w [K][N] fp32 -> wqT [N][K] fp8. LDS tile u32 [64][17] (pad -> <=2-way
// banks = free). Phase 1: coalesced float4 load, pack, u32 LDS write.
// Phase 2: 4 u32 reads + register byte-transpose + 4 coalesced u32 stores.
__global__ __launch_bounds__(256) void wquant_kernel(
    const float* __restrict__ w, uint8_t* __restrict__ wqT)
{
    const int n0 = blockIdx.x * 64;
    const int k0 = blockIdx.y * 64;
    __shared__ uint32_t tile[64][17]; // [k][n-group], +1 pad

#pragma unroll
    for (int e = 0; e < 4; ++e) {
        int idx = threadIdx.x + e * 256; // 0..1023
        int r = idx >> 4;                // k within tile
        int c4 = idx & 15;               // n u32 group
        float4 v = *(const float4*)(w + (size_t)(k0 + r) * N_DIM + n0 + c4 * 4);
        tile[r][c4] = pack4_fp8(v.x, v.y, v.z, v.w);
    }
    __syncthreads();
    // one (ng,kg) pair per thread: 4 input u32s -> byte transpose -> 4 outputs
    const int kg = threadIdx.x & 15;   // k u32 group
    const int ng = threadIdx.x >> 4;   // n group of 4 rows
    uint32_t in0 = tile[kg * 4 + 0][ng];
    uint32_t in1 = tile[kg * 4 + 1][ng];
    uint32_t in2 = tile[kg * 4 + 2][ng];
    uint32_t in3 = tile[kg * 4 + 3][ng];
#pragma unroll
    for (int i = 0; i < 4; ++i) {
        uint32_t o = ((in0 >> (8 * i)) & 0xFFu)
                   | (((in1 >> (8 * i)) & 0xFFu) << 8)
                   | (((in2 >> (8 * i)) & 0xFFu) << 16)
                   | (((in3 >> (8 * i)) & 0xFFu) << 24);
        *(uint32_t*)(wqT + (size_t)(n0 + ng * 4 + i) * K_DIM + k0 + kg * 4) = o;
    }
}

// ---------- kernel 3: fp8 GEMM, MX-scaled K=128 with unit scales ----------
// 128x128 tile, BK=128B, 4 waves 2x2 (64x64 each, 4x4 of 16x16).
// mfma_scale_f32_16x16x128_f8f6f4 with e8m0 scale 0x7F (=1.0): numerics
// identical to non-scaled fp8, 2x the MFMA rate (m148: 995->1628 TF).
// LDS XOR-16B swizzle over 8 groups; slot gg = g ^ (row&7) cancels on read,
// so each lane reads its standard k in [quad*32, quad*32+32).
__global__ __launch_bounds__(256) void gemm_fp8_kernel(
    const uint8_t* __restrict__ xq, const uint8_t* __restrict__ wqT,
    const float* __restrict__ xscale, const float* __restrict__ wscale,
    float* __restrict__ out)
{
    __shared__ __align__(16) uint8_t As[128 * 128]; // [m][k-swizzled] 16 KB
    __shared__ __align__(16) uint8_t Bs[128 * 128]; // [n][k-swizzled] 16 KB

    const int tid = threadIdx.x;
    const int lane = tid & 63;
    const int wave = tid >> 6;
    const int m0 = blockIdx.y * 128;
    const int n0 = blockIdx.x * 128;
    const int wm = (wave >> 1) * 64;
    const int wn = (wave & 1) * 64;
    const int row = lane & 15;
    const int quad = lane >> 4;

    floatx4 acc[4][4] = {{{0.f,0.f,0.f,0.f}}};

    // staging: 1024 chunks of 16B per matrix; 4 per thread per matrix.
    // LDS slot c=(r,gg) holds global group g = gg ^ (r&7); LDS dest stays
    // lane-contiguous (HW constraint), global addr is per-lane free.
    const uint8_t* gA[4];
    const uint8_t* gB[4];
    uint8_t* lA[4];
    uint8_t* lB[4];
#pragma unroll
    for (int p = 0; p < 4; ++p) {
        const int c = tid + p * 256;
        const int r = c >> 3, gg = c & 7, g = gg ^ (r & 7);
        gA[p] = xq  + (size_t)(m0 + r) * K_DIM + g * 16;
        gB[p] = wqT + (size_t)(n0 + r) * K_DIM + g * 16;
        lA[p] = As + c * 16;
        lB[p] = Bs + c * 16;
    }

    // frag read offsets: two b128 per frag row, slot groups (2q+s)^(row&7)
    int aoff0[4], aoff1[4], boff0[4], boff1[4];
#pragma unroll
    for (int i = 0; i < 4; ++i) {
        const int mr = wm + i * 16 + row;
        const int nr = wn + i * 16 + row;
        aoff0[i] = mr * 128 + (((2 * quad)     ^ (mr & 7)) << 4);
        aoff1[i] = mr * 128 + (((2 * quad + 1) ^ (mr & 7)) << 4);
        boff0[i] = nr * 128 + (((2 * quad)     ^ (nr & 7)) << 4);
        boff1[i] = nr * 128 + (((2 * quad + 1) ^ (nr & 7)) << 4);
    }

    for (int k0 = 0; k0 < K_DIM; k0 += 128) {
        __syncthreads();
#pragma unroll
        for (int p = 0; p < 4; ++p) {
            load16_g2lds(gA[p] + k0, lA[p]);
            load16_g2lds(gB[p] + k0, lB[p]);
        }
        __syncthreads();

        intx8 a[4], b[4];
#pragma unroll
        for (int i = 0; i < 4; ++i) {
            intx4 lo = *(const intx4*)(As + aoff0[i]);
            intx4 hi = *(const intx4*)(As + aoff1[i]);
            a[i] = __builtin_shufflevector(lo, hi, 0, 1, 2, 3, 4, 5, 6, 7);
        }
#pragma unroll
        for (int j = 0; j < 4; ++j) {
            intx4 lo = *(const intx4*)(Bs + boff0[j]);
            intx4 hi = *(const intx4*)(Bs + boff1[j]);
            b[j] = __builtin_shufflevector(lo, hi, 0, 1, 2, 3, 4, 5, 6, 7);
        }
#pragma unroll
        for (int i = 0; i < 4; ++i)
#pragma unroll
            for (int j = 0; j < 4; ++j)
                acc[i][j] = __builtin_amdgcn_mfma_scale_f32_16x16x128_f8f6f4(
                    a[i], b[j], acc[i][j],
                    0, 0,                    // cbsz=fp8(e4m3), blgp=fp8(e4m3)
                    0, 0x7F7F7F7F,           // A scale: e8m0 127 = 1.0
                    0, 0x7F7F7F7F);          // B scale: 1.0
    }

    // epilogue: C/D layout col=lane&15, row=quad*4+reg (shape-determined)
    const float wsv = wscale[0];
#pragma unroll
    for (int i = 0; i < 4; ++i) {
        const int rbase = m0 + wm + i * 16 + quad * 4;
        float s[4];
#pragma unroll
        for (int r = 0; r < 4; ++r) s[r] = xscale[rbase + r] * wsv;
#pragma unroll
        for (int j = 0; j < 4; ++j) {
            const int col = n0 + wn + j * 16 + row;
#pragma unroll
            for (int r = 0; r < 4; ++r)
                out[(size_t)(rbase + r) * N_DIM + col] = acc[i][j][r] * s[r];
        }
    }
}

// ---------- launch ----------

extern "C" void kernel_launch(void* const* d_in, const int* in_sizes, int n_in,
                              void* d_out, int out_size, void* d_ws, size_t ws_size,
                              hipStream_t stream) {
    const float* x      = (const float*)d_in[0]; // [8192,4096] fp32
    const float* w      = (const float*)d_in[1]; // [4096,4096] fp32
    const float* wscale = (const float*)d_in[2]; // [1] fp32
    float* out = (float*)d_out;                  // [8192,4096] fp32

    uint8_t* xq  = (uint8_t*)d_ws;
    uint8_t* wqT = xq + (size_t)T_DIM * K_DIM;
    float* xscale = (float*)(wqT + (size_t)N_DIM * K_DIM);

    xquant_kernel<<<T_DIM, 256, 0, stream>>>(x, xq, xscale);
    wquant_kernel<<<dim3(N_DIM / 64, K_DIM / 64), 256, 0, stream>>>(w, wqT);
    gemm_fp8_kernel<<<dim3(N_DIM / 128, T_DIM / 128), 256, 0, stream>>>(
        xq, wqT, xscale, wscale, out);
}

// Round 4
// 391.217 us; speedup vs baseline: 2.0989x; 1.0439x over previous
//
#include <hip/hip_runtime.h>
#include <stdint.h>

#define T_DIM 8192
#define K_DIM 4096
#define N_DIM 4096
#define FP8MAX 448.0f

typedef __attribute__((ext_vector_type(4))) float floatx4;
typedef __attribute__((ext_vector_type(4))) int   intx4;
typedef __attribute__((ext_vector_type(8))) int   intx8;

// ---------- helpers ----------

__device__ static inline void load16_g2lds(const void* gptr, void* lptr) {
    __builtin_amdgcn_global_load_lds(
        (const __attribute__((address_space(1))) void*)gptr,
        (__attribute__((address_space(3))) void*)lptr,
        16, 0, 0);
}

// pack 4 floats -> 4 fp8 e4m3fn bytes (HW RNE cvt; OCP format on gfx950)
__device__ static inline uint32_t pack4_fp8(float f0, float f1, float f2, float f3) {
    int p = 0;
    p = __builtin_amdgcn_cvt_pk_fp8_f32(f0, f1, p, false); // bytes 0,1
    p = __builtin_amdgcn_cvt_pk_fp8_f32(f2, f3, p, true);  // bytes 2,3
    return (uint32_t)p;
}

// ---------- kernel 1: fused quantization ----------
// blocks [0, T_DIM): per-row dynamic quant of x -> xq + xscale
// blocks [T_DIM, T_DIM + 4096): quantize+transpose w -> wqT (64x64 tiles)
__global__ __launch_bounds__(256) void quant_fused_kernel(
    const float* __restrict__ x, const float* __restrict__ w,
    uint8_t* __restrict__ xq, uint8_t* __restrict__ wqT,
    float* __restrict__ xscale)
{
    const int tid = threadIdx.x;
    if (blockIdx.x < T_DIM) {
        // ---- x quant: one block per row ----
        const int t = blockIdx.x;
        const int lane = tid & 63;
        const int wave = tid >> 6;
        const float4* xr4 = (const float4*)(x + (size_t)t * K_DIM);

        float4 v[4];
        float m = 0.0f;
#pragma unroll
        for (int e = 0; e < 4; ++e) {
            v[e] = xr4[tid + e * 256];
            m = fmaxf(m, fmaxf(fmaxf(fabsf(v[e].x), fabsf(v[e].y)),
                               fmaxf(fabsf(v[e].z), fabsf(v[e].w))));
        }
#pragma unroll
        for (int off = 32; off > 0; off >>= 1)
            m = fmaxf(m, __shfl_down(m, off, 64));
        __shared__ float red[4];
        if (lane == 0) red[wave] = m;
        __syncthreads();
        float mm = fmaxf(fmaxf(red[0], red[1]), fmaxf(red[2], red[3]));
        float scale = fmaxf(mm / FP8MAX, 1e-12f); // exact ref semantics
        if (tid == 0) xscale[t] = scale;
        const float inv = 1.0f / scale;

        uint32_t* xqr = (uint32_t*)(xq + (size_t)t * K_DIM);
#pragma unroll
        for (int e = 0; e < 4; ++e) {
            float q0 = fminf(fmaxf(v[e].x * inv, -FP8MAX), FP8MAX);
            float q1 = fminf(fmaxf(v[e].y * inv, -FP8MAX), FP8MAX);
            float q2 = fminf(fmaxf(v[e].z * inv, -FP8MAX), FP8MAX);
            float q3 = fminf(fmaxf(v[e].w * inv, -FP8MAX), FP8MAX);
            xqr[tid + e * 256] = pack4_fp8(q0, q1, q2, q3);
        }
    } else {
        // ---- w quant + transpose: 64x64 tile per block, u32-granular ----
        const int b = blockIdx.x - T_DIM;
        const int n0 = (b & 63) * 64;
        const int k0 = (b >> 6) * 64;
        __shared__ uint32_t tile[64][17]; // [k][n-group], +1 pad

#pragma unroll
        for (int e = 0; e < 4; ++e) {
            int idx = tid + e * 256; // 0..1023
            int r = idx >> 4;        // k within tile
            int c4 = idx & 15;       // n u32 group
            float4 v = *(const float4*)(w + (size_t)(k0 + r) * N_DIM + n0 + c4 * 4);
            tile[r][c4] = pack4_fp8(v.x, v.y, v.z, v.w);
        }
        __syncthreads();
        const int kg = tid & 15;   // k u32 group
        const int ng = tid >> 4;   // n group of 4 rows
        uint32_t in0 = tile[kg * 4 + 0][ng];
        uint32_t in1 = tile[kg * 4 + 1][ng];
        uint32_t in2 = tile[kg * 4 + 2][ng];
        uint32_t in3 = tile[kg * 4 + 3][ng];
#pragma unroll
        for (int i = 0; i < 4; ++i) {
            uint32_t o = ((in0 >> (8 * i)) & 0xFFu)
                       | (((in1 >> (8 * i)) & 0xFFu) << 8)
                       | (((in2 >> (8 * i)) & 0xFFu) << 16)
                       | (((in3 >> (8 * i)) & 0xFFu) << 24);
            *(uint32_t*)(wqT + (size_t)(n0 + ng * 4 + i) * K_DIM + k0 + kg * 4) = o;
        }
    }
}

// ---------- kernel 2: fp8 GEMM, MX-scaled K=128 with unit scales ----------
// 128x128 tile, BK=128B, 4 waves 2x2 (64x64 each, 4x4 of 16x16).
// mfma_scale_f32_16x16x128_f8f6f4 with e8m0 scale 0x7F (=1.0): numerics
// identical to non-scaled fp8, 2x rate. LDS XOR-16B swizzle over 8 groups;
// slot gg = g ^ (row&7) cancels on read -> identity k-mapping.
// __launch_bounds__(256,3): forces VGPR+AGPR <= 170 -> 3 waves/EU (R3 was 2).
__global__ __launch_bounds__(256, 3) void gemm_fp8_kernel(
    const uint8_t* __restrict__ xq, const uint8_t* __restrict__ wqT,
    const float* __restrict__ xscale, const float* __restrict__ wscale,
    float* __restrict__ out)
{
    __shared__ __align__(16) uint8_t As[128 * 128]; // [m][k-swizzled] 16 KB
    __shared__ __align__(16) uint8_t Bs[128 * 128]; // [n][k-swizzled] 16 KB

    const int tid = threadIdx.x;
    const int lane = tid & 63;
    const int wave = tid >> 6;
    const int m0 = blockIdx.y * 128;
    const int n0 = blockIdx.x * 128;
    const int wm = (wave >> 1) * 64;
    const int wn = (wave & 1) * 64;
    const int row = lane & 15;
    const int quad = lane >> 4;

    floatx4 acc[4][4] = {{{0.f,0.f,0.f,0.f}}};

    // staging: 1024 chunks of 16B per matrix; 4 per thread per matrix.
    // LDS slot c=(r,gg) holds global group g = gg ^ (r&7).
    const uint8_t* gA[4];
    const uint8_t* gB[4];
    uint8_t* lA[4];
    uint8_t* lB[4];
#pragma unroll
    for (int p = 0; p < 4; ++p) {
        const int c = tid + p * 256;
        const int r = c >> 3, gg = c & 7, g = gg ^ (r & 7);
        gA[p] = xq  + (size_t)(m0 + r) * K_DIM + g * 16;
        gB[p] = wqT + (size_t)(n0 + r) * K_DIM + g * 16;
        lA[p] = As + c * 16;
        lB[p] = Bs + c * 16;
    }

    // frag read offsets: two b128 per frag row, slot groups (2q+s)^(row&7)
    int aoff0[4], aoff1[4], boff0[4], boff1[4];
#pragma unroll
    for (int i = 0; i < 4; ++i) {
        const int mr = wm + i * 16 + row;
        const int nr = wn + i * 16 + row;
        aoff0[i] = mr * 128 + (((2 * quad)     ^ (mr & 7)) << 4);
        aoff1[i] = mr * 128 + (((2 * quad + 1) ^ (mr & 7)) << 4);
        boff0[i] = nr * 128 + (((2 * quad)     ^ (nr & 7)) << 4);
        boff1[i] = nr * 128 + (((2 * quad + 1) ^ (nr & 7)) << 4);
    }

    for (int k0 = 0; k0 < K_DIM; k0 += 128) {
        __syncthreads();
#pragma unroll
        for (int p = 0; p < 4; ++p) {
            load16_g2lds(gA[p] + k0, lA[p]);
            load16_g2lds(gB[p] + k0, lB[p]);
        }
        __syncthreads();

        intx8 a[4], b[4];
#pragma unroll
        for (int i = 0; i < 4; ++i) {
            intx4 lo = *(const intx4*)(As + aoff0[i]);
            intx4 hi = *(const intx4*)(As + aoff1[i]);
            a[i] = __builtin_shufflevector(lo, hi, 0, 1, 2, 3, 4, 5, 6, 7);
        }
#pragma unroll
        for (int j = 0; j < 4; ++j) {
            intx4 lo = *(const intx4*)(Bs + boff0[j]);
            intx4 hi = *(const intx4*)(Bs + boff1[j]);
            b[j] = __builtin_shufflevector(lo, hi, 0, 1, 2, 3, 4, 5, 6, 7);
        }
#pragma unroll
        for (int i = 0; i < 4; ++i)
#pragma unroll
            for (int j = 0; j < 4; ++j)
                acc[i][j] = __builtin_amdgcn_mfma_scale_f32_16x16x128_f8f6f4(
                    a[i], b[j], acc[i][j],
                    0, 0,                    // cbsz=fp8(e4m3), blgp=fp8(e4m3)
                    0, 0x7F7F7F7F,           // A scale: e8m0 127 = 1.0
                    0, 0x7F7F7F7F);          // B scale: 1.0
    }

    // epilogue: C/D layout col=lane&15, row=quad*4+reg (shape-determined)
    const float wsv = wscale[0];
#pragma unroll
    for (int i = 0; i < 4; ++i) {
        const int rbase = m0 + wm + i * 16 + quad * 4;
        float s[4];
#pragma unroll
        for (int r = 0; r < 4; ++r) s[r] = xscale[rbase + r] * wsv;
#pragma unroll
        for (int j = 0; j < 4; ++j) {
            const int col = n0 + wn + j * 16 + row;
#pragma unroll
            for (int r = 0; r < 4; ++r)
                out[(size_t)(rbase + r) * N_DIM + col] = acc[i][j][r] * s[r];
        }
    }
}

// ---------- launch ----------

extern "C" void kernel_launch(void* const* d_in, const int* in_sizes, int n_in,
                              void* d_out, int out_size, void* d_ws, size_t ws_size,
                              hipStream_t stream) {
    const float* x      = (const float*)d_in[0]; // [8192,4096] fp32
    const float* w      = (const float*)d_in[1]; // [4096,4096] fp32
    const float* wscale = (const float*)d_in[2]; // [1] fp32
    float* out = (float*)d_out;                  // [8192,4096] fp32

    uint8_t* xq  = (uint8_t*)d_ws;
    uint8_t* wqT = xq + (size_t)T_DIM * K_DIM;
    float* xscale = (float*)(wqT + (size_t)N_DIM * K_DIM);

    quant_fused_kernel<<<T_DIM + (N_DIM / 64) * (K_DIM / 64), 256, 0, stream>>>(
        x, w, xq, wqT, xscale);
    gemm_fp8_kernel<<<dim3(N_DIM / 128, T_DIM / 128), 256, 0, stream>>>(
        xq, wqT, xscale, wscale, out);
}